// Round 3
// baseline (328.256 us; speedup 1.0000x reference)
//
#include <hip/hip_runtime.h>
#include <hip/hip_bf16.h>

// ElasticMLP fused: 8 layers, H=128, B=262144, relu each layer, skip(+x) for l>0.
//
// Round-3: wave-private activations. One wave owns 32 batches x all 128 neurons
// (4 m-tiles of mfma_f32_32x32x16_bf16, A = W, B = h). The next layer's B-frags
// are built from this wave's C-frags with ONE shfl_xor(32) exchange per k-step:
// h never touches LDS, no h barriers. LDS holds only W (2 x 32KB double buffer,
// XOR-swizzled 16B chunks: phys_chunk = t ^ (m&7) -> conflict-free b128 reads).
// One barrier per layer (W buffer flip). Bias from bf16 copy, folded into acc init.
// x kept fp32 in registers (C-layout) for exact skip-adds.

typedef __bf16 bf16_t;
typedef __bf16 bf16x4 __attribute__((ext_vector_type(4)));
typedef __bf16 bf16x8 __attribute__((ext_vector_type(8)));
typedef float floatx4 __attribute__((ext_vector_type(4)));
typedef float floatx16 __attribute__((ext_vector_type(16)));
typedef unsigned int uint2v __attribute__((ext_vector_type(2)));
typedef unsigned int uint4v __attribute__((ext_vector_type(4)));

#define HID 128
#define NL 8

__global__ __launch_bounds__(256) void wconv_kernel(const float* __restrict__ w,
                                                    const float* __restrict__ b,
                                                    bf16_t* __restrict__ wb,
                                                    bf16_t* __restrict__ bb) {
    if (blockIdx.x < 128) {
        int i = (blockIdx.x * 256 + threadIdx.x) * 4;   // 131072 W elems
        floatx4 v = *(const floatx4*)&w[i];
        bf16x4 o = { (bf16_t)v[0], (bf16_t)v[1], (bf16_t)v[2], (bf16_t)v[3] };
        *(bf16x4*)&wb[i] = o;
    } else {
        int i = threadIdx.x * 4;                        // 1024 bias elems
        floatx4 v = *(const floatx4*)&b[i];
        bf16x4 o = { (bf16_t)v[0], (bf16_t)v[1], (bf16_t)v[2], (bf16_t)v[3] };
        *(bf16x4*)&bb[i] = o;
    }
}

// Build next-layer B-frags from C-layout values hv[tile][reg].
// Derivation (C/D: row=(r&3)+8*(r>>2)+4H, col=c; B: n=c, k=8H+j within step):
// step s: tile t=s>>1, q=s&1. Dest lane H=0: j0-3 = own regs 8q..+3,
// j4-7 = lane^32 regs 8q..+3. Dest H=1: j0-3 = lane^32 regs 8q+4..+7,
// j4-7 = own regs 8q+4..+7.  => one bf16x4 (2 dword) xor-32 exchange per step.
__device__ __forceinline__ void build_bfrag(const floatx16 hv[4], int H, bf16x8 bfr[8]) {
#pragma unroll
    for (int t = 0; t < 4; ++t)
#pragma unroll
        for (int q = 0; q < 2; ++q) {
            bf16x4 plo = { (bf16_t)hv[t][8*q+0], (bf16_t)hv[t][8*q+1],
                           (bf16_t)hv[t][8*q+2], (bf16_t)hv[t][8*q+3] };
            bf16x4 phi = { (bf16_t)hv[t][8*q+4], (bf16_t)hv[t][8*q+5],
                           (bf16_t)hv[t][8*q+6], (bf16_t)hv[t][8*q+7] };
            uint2v ulo = __builtin_bit_cast(uint2v, plo);
            uint2v uhi = __builtin_bit_cast(uint2v, phi);
            unsigned sx = H ? ulo[0] : uhi[0];
            unsigned sy = H ? ulo[1] : uhi[1];
            unsigned rx = (unsigned)__shfl_xor((int)sx, 32, 64);
            unsigned ry = (unsigned)__shfl_xor((int)sy, 32, 64);
            uint4v u;
            u[0] = H ? rx : ulo[0];
            u[1] = H ? ry : ulo[1];
            u[2] = H ? uhi[0] : rx;
            u[3] = H ? uhi[1] : ry;
            bfr[2*t + q] = __builtin_bit_cast(bf16x8, u);
        }
}

__global__ __launch_bounds__(256, 2) void mlp_kernel(
    const float* __restrict__ x, const bf16_t* __restrict__ wb,
    const bf16_t* __restrict__ bb, float* __restrict__ out)
{
    __shared__ __align__(16) bf16_t wsh[2][HID * HID];   // 2 x 32KB, xor-swizzled

    const int tid  = threadIdx.x;
    const int wave = tid >> 6;
    const int lane = tid & 63;
    const int H = lane >> 5;           // wave half
    const int c = lane & 31;           // batch-in-wave (B col / C col / A m-row)
    const long gb = ((long)blockIdx.x * 4 + wave) * 32;
    const float* xrow = x + (gb + c) * HID;

    // x chunks [mi][g] = x[gb+c][32mi+8g+4H .. +3]  (== C regs 4g..4g+3 of tile mi)
    floatx4 xr[4][4];
#pragma unroll
    for (int mi = 0; mi < 4; ++mi)
#pragma unroll
        for (int g = 0; g < 4; ++g)
            xr[mi][g] = *(const floatx4*)&xrow[32*mi + 8*g + 4*H];

    // stage W0: global (flat, coalesced) -> regs -> swizzled LDS
    const bf16x8* wbv = (const bf16x8*)wb;   // 2048 16B chunks per layer
    bf16x8 wstg[8];
#pragma unroll
    for (int p = 0; p < 8; ++p) wstg[p] = wbv[p*256 + tid];

    // layer-0 B-frags straight from xr (no relu/bias/skip)
    bf16x8 bfr[8];
    {
        floatx16 hv[4];
#pragma unroll
        for (int t = 0; t < 4; ++t)
#pragma unroll
            for (int r = 0; r < 16; ++r)
                hv[t][r] = xr[t][r >> 2][r & 3];
        build_bfrag(hv, H, bfr);
    }

#pragma unroll
    for (int p = 0; p < 8; ++p) {
        int f = p*256 + tid;
        int m = f >> 4, t = f & 15;
        *(bf16x8*)&wsh[0][m*HID + ((t ^ (m & 7)) * 8)] = wstg[p];
    }
    __syncthreads();

    for (int l = 0; l < NL; ++l) {
        // acc init = bias (bf16 JIT loads, L2-hot; acc reg r <-> chunk (g=r>>2,k=r&3))
        floatx16 acc[4];
#pragma unroll
        for (int mi = 0; mi < 4; ++mi)
#pragma unroll
            for (int g = 0; g < 4; ++g) {
                bf16x4 bv = *(const bf16x4*)&bb[l*HID + 32*mi + 8*g + 4*H];
#pragma unroll
                for (int k = 0; k < 4; ++k) acc[mi][4*g + k] = (float)bv[k];
            }

        // prefetch next layer W into regs (overlaps this layer's MFMAs)
        if (l + 1 < NL) {
#pragma unroll
            for (int p = 0; p < 8; ++p) wstg[p] = wbv[(l+1)*2048 + p*256 + tid];
        }

        // MFMA over 8 k-steps; A-frags streamed from swizzled LDS (conflict-free)
        const bf16_t* wbuf = wsh[l & 1];
        bf16x8 wf[2][4];
#pragma unroll
        for (int mi = 0; mi < 4; ++mi)
            wf[0][mi] = *(const bf16x8*)&wbuf[(32*mi + c)*HID + ((H ^ (c & 7)) * 8)];
#pragma unroll
        for (int s = 0; s < 8; ++s) {
            if (s + 1 < 8) {
                const int tc = 2*(s+1) + H;
#pragma unroll
                for (int mi = 0; mi < 4; ++mi)
                    wf[(s+1) & 1][mi] =
                        *(const bf16x8*)&wbuf[(32*mi + c)*HID + ((tc ^ (c & 7)) * 8)];
            }
#pragma unroll
            for (int mi = 0; mi < 4; ++mi)
                acc[mi] = __builtin_amdgcn_mfma_f32_32x32x16_bf16(
                              wf[s & 1][mi], bfr[s], acc[mi], 0, 0, 0);
        }

        // stage W(l+1) into the other buffer (current reads used buf l&1)
        if (l + 1 < NL) {
#pragma unroll
            for (int p = 0; p < 8; ++p) {
                int f = p*256 + tid;
                int m = f >> 4, t = f & 15;
                *(bf16x8*)&wsh[(l+1) & 1][m*HID + ((t ^ (m & 7)) * 8)] = wstg[p];
            }
        }

        if (l < NL - 1) {
            // epilogue: h' = relu(acc) (+x for l>0); next B-frags in-register
            floatx16 hv[4];
#pragma unroll
            for (int mi = 0; mi < 4; ++mi)
#pragma unroll
                for (int r = 0; r < 16; ++r) {
                    float v = fmaxf(acc[mi][r], 0.0f);
                    if (l > 0) v += xr[mi][r >> 2][r & 3];
                    hv[mi][r] = v;
                }
            build_bfrag(hv, H, bfr);
            __syncthreads();   // W(l+1) staged & visible before next-layer reads
        } else {
            // last layer: relu + skip, fp32 dwordx4 stores
            float* orow = out + (gb + c) * HID;
#pragma unroll
            for (int mi = 0; mi < 4; ++mi)
#pragma unroll
                for (int g = 0; g < 4; ++g) {
                    floatx4 o;
#pragma unroll
                    for (int k = 0; k < 4; ++k)
                        o[k] = fmaxf(acc[mi][4*g + k], 0.0f) + xr[mi][g][k];
                    *(floatx4*)&orow[32*mi + 8*g + 4*H] = o;
                }
        }
    }
}

extern "C" void kernel_launch(void* const* d_in, const int* in_sizes, int n_in,
                              void* d_out, int out_size, void* d_ws, size_t ws_size,
                              hipStream_t stream) {
    const float* x = (const float*)d_in[0];    // 262144*128
    const float* w = (const float*)d_in[1];    // 8*128*128
    const float* b = (const float*)d_in[2];    // 8*128
    float* out = (float*)d_out;
    bf16_t* wb = (bf16_t*)d_ws;                        // 131072 bf16
    bf16_t* bbb = (bf16_t*)d_ws + 131072;              // 1024 bf16

    wconv_kernel<<<129, 256, 0, stream>>>(w, b, wb, bbb);

    const int nblocks = 262144 / 128;          // 2048 blocks x 4 waves x 32 batches
    mlp_kernel<<<nblocks, 256, 0, stream>>>(x, wb, bbb, out);
}